// Round 1
// baseline (467.785 us; speedup 1.0000x reference)
//
#include <hip/hip_runtime.h>
#include <math.h>

// Problem constants (match reference)
#define N_ATOMS 768
#define FD 128          // feature width F
#define NRBF 32
#define MAXN 96         // neighbor-list capacity (mean ~26, Poisson tail safe)

constexpr float  CUT2   = 25.0f;
constexpr float  GAMMA_ = 40.96f;            // 1/(5/32)^2
constexpr float  CSTEP  = 5.0f / 31.0f;      // linspace(0,5,32) step
constexpr double KB_D   = 8.617330337217213e-05;
constexpr double KT_D   = 300.0 * KB_D;
constexpr float  KT_F   = (float)KT_D;
constexpr float  TARGET_KE = (float)(0.5 * 2304.0 * KT_D);
constexpr float  Q0_F   = (float)(2.0 * 2304.0 * KT_D * 400.0);  // Q[0]
constexpr float  QI_F   = (float)(2.0 * KT_D * 400.0);           // Q[1..3]

#define DVDT_OFF 0
#define V_OFF    (3 * N_ATOMS)
#define PETA_OFF (6 * N_ATOMS)

// ---------------------------------------------------------------- prep
// h = embed[z], W2T/W3T transposes (for coalesced backward access)
__global__ __launch_bounds__(256) void prep_kernel(
    const int* __restrict__ z, const float* __restrict__ embed,
    const float* __restrict__ W2, const float* __restrict__ W3,
    float* __restrict__ h, float* __restrict__ W2T, float* __restrict__ W3T)
{
    int idx = blockIdx.x * 256 + threadIdx.x;
    if (idx < N_ATOMS * FD) {
        int a = idx >> 7, f = idx & 127;
        h[idx] = embed[z[a] * FD + f];
    }
    if (idx < FD * FD) {
        int f = idx >> 7, c = idx & 127;
        W2T[c * FD + f] = W2[idx];
        W3T[c * FD + f] = W3[idx];
    }
}

// ---------------------------------------------------------------- neighbor list
__global__ __launch_bounds__(256) void nbr_kernel(
    const float* __restrict__ q, int* __restrict__ nbr_cnt, int* __restrict__ nbr_idx)
{
    __shared__ int c;
    int i = blockIdx.x;
    if (threadIdx.x == 0) c = 0;
    __syncthreads();
    float qx = q[i*3], qy = q[i*3+1], qz = q[i*3+2];
    for (int j = threadIdx.x; j < N_ATOMS; j += 256) {
        if (j == i) continue;
        float dx = qx - q[j*3], dy = qy - q[j*3+1], dz = qz - q[j*3+2];
        float d2 = dx*dx + dy*dy + dz*dz;
        if (d2 < CUT2) {
            int p = atomicAdd(&c, 1);
            if (p < MAXN) nbr_idx[i * MAXN + p] = j;
        }
    }
    __syncthreads();
    if (threadIdx.x == 0) nbr_cnt[i] = min(c, MAXN);
}

// ---------------------------------------------------------------- forward messages
// m[i,f] = sum_{j in nbr(i)} filt_ij[f] * h[j,f]
// filt = relu(rbf@W1 + b1) @ W2 + b2
__global__ __launch_bounds__(128) void fwd_kernel(
    const float* __restrict__ q, const float* __restrict__ W1,
    const float* __restrict__ b1, const float* __restrict__ W2,
    const float* __restrict__ b2, const float* __restrict__ h,
    const int* __restrict__ nbr_cnt, const int* __restrict__ nbr_idx,
    float* __restrict__ m_out)
{
    extern __shared__ float smem[];
    float* W2s   = smem;                 // 16384
    float* rbf_s = W2s + FD * FD;        // 32
    float* a1_s  = rbf_s + NRBF;         // 128

    int i = blockIdx.x, t = threadIdx.x;
    // stage W2 into LDS (coalesced float4)
    for (int r = t; r < FD * FD / 4; r += 128)
        ((float4*)W2s)[r] = ((const float4*)W2)[r];
    // W1 column t into registers
    float w1r[NRBF];
#pragma unroll
    for (int k = 0; k < NRBF; k++) w1r[k] = W1[k * FD + t];

    float qx = q[i*3], qy = q[i*3+1], qz = q[i*3+2];
    float b1t = b1[t], b2t = b2[t];
    int cnt = nbr_cnt[i];
    const int* nlist = nbr_idx + i * MAXN;
    float acc = 0.f;
    __syncthreads();

    for (int jj = 0; jj < cnt; jj++) {
        int j = nlist[jj];
        float dx = qx - q[j*3], dy = qy - q[j*3+1], dz = qz - q[j*3+2];
        float d = sqrtf(dx*dx + dy*dy + dz*dz);
        if (t < NRBF) {
            float u = d - CSTEP * (float)t;
            rbf_s[t] = expf(-GAMMA_ * u * u);
        }
        __syncthreads();
        float u1 = b1t;
#pragma unroll
        for (int k = 0; k < NRBF; k++) u1 += rbf_s[k] * w1r[k];
        a1_s[t] = fmaxf(u1, 0.f);
        __syncthreads();
        float s0 = 0.f, s1 = 0.f, s2 = 0.f, s3 = 0.f;
#pragma unroll 8
        for (int f = 0; f < FD; f += 4) {
            s0 += a1_s[f]   * W2s[(f)   * FD + t];
            s1 += a1_s[f+1] * W2s[(f+1) * FD + t];
            s2 += a1_s[f+2] * W2s[(f+2) * FD + t];
            s3 += a1_s[f+3] * W2s[(f+3) * FD + t];
        }
        float filt = b2t + ((s0 + s1) + (s2 + s3));
        acc += filt * h[j * FD + t];
        __syncthreads();   // protect rbf_s/a1_s before next iteration
    }
    m_out[i * FD + t] = acc;
}

// ---------------------------------------------------------------- per-atom backward head
// gbar = w_out * 1[(m@W3)>0];  mbar = W3 @ gbar
__global__ __launch_bounds__(128) void mbar_kernel(
    const float* __restrict__ m, const float* __restrict__ W3,
    const float* __restrict__ W3T, const float* __restrict__ w_out,
    float* __restrict__ mbar)
{
    __shared__ float ms[FD];
    __shared__ float gb[FD];
    int i = blockIdx.x, t = threadIdx.x;
    ms[t] = m[i * FD + t];
    __syncthreads();
    float g = 0.f;
#pragma unroll 8
    for (int f = 0; f < FD; f++) g += ms[f] * W3[f * FD + t];
    gb[t] = (g > 0.f) ? w_out[t] : 0.f;
    __syncthreads();
    float mb = 0.f;
#pragma unroll 8
    for (int c = 0; c < FD; c++) mb += gb[c] * W3T[c * FD + t];
    mbar[i * FD + t] = mb;
}

// ---------------------------------------------------------------- per-pair backward
// s_ij = dE/dd_ij stored dense S[i][j]
__global__ __launch_bounds__(128) void bwd_kernel(
    const float* __restrict__ q, const float* __restrict__ W1,
    const float* __restrict__ b1, const float* __restrict__ W2T,
    const float* __restrict__ h, const float* __restrict__ mbar,
    const int* __restrict__ nbr_cnt, const int* __restrict__ nbr_idx,
    float* __restrict__ S)
{
    extern __shared__ float smem[];
    float* W2Ts   = smem;                  // 16384 (W2T[c][f])
    float* rbf_s  = W2Ts + FD * FD;        // 32
    float* crbf_s = rbf_s + NRBF;          // 32
    float* t_s    = crbf_s + NRBF;         // 128
    float* red    = t_s + FD;              // 2

    int i = blockIdx.x, t = threadIdx.x;
    for (int r = t; r < FD * FD / 4; r += 128)
        ((float4*)W2Ts)[r] = ((const float4*)W2T)[r];
    float w1r[NRBF];
#pragma unroll
    for (int k = 0; k < NRBF; k++) w1r[k] = W1[k * FD + t];

    float qx = q[i*3], qy = q[i*3+1], qz = q[i*3+2];
    float b1t = b1[t];
    float mb  = mbar[i * FD + t];
    int cnt = nbr_cnt[i];
    const int* nlist = nbr_idx + i * MAXN;
    __syncthreads();

    for (int jj = 0; jj < cnt; jj++) {
        int j = nlist[jj];
        float dx = qx - q[j*3], dy = qy - q[j*3+1], dz = qz - q[j*3+2];
        float d = sqrtf(dx*dx + dy*dy + dz*dz);
        if (t < NRBF) {
            float u = d - CSTEP * (float)t;
            float r = expf(-GAMMA_ * u * u);
            rbf_s[t]  = r;
            crbf_s[t] = -2.f * GAMMA_ * u * r;   // d(rbf)/dd
        }
        t_s[t] = mb * h[j * FD + t];             // dE/dfilt
        __syncthreads();
        float u1 = b1t, ef = 0.f;
#pragma unroll
        for (int k = 0; k < NRBF; k++) {
            u1 += rbf_s[k]  * w1r[k];
            ef += crbf_s[k] * w1r[k];            // e_f = sum_k crbf_k W1[k,f]
        }
        float s0 = 0.f, s1 = 0.f, s2 = 0.f, s3 = 0.f;
#pragma unroll 8
        for (int c = 0; c < FD; c += 4) {
            s0 += t_s[c]   * W2Ts[(c)   * FD + t];
            s1 += t_s[c+1] * W2Ts[(c+1) * FD + t];
            s2 += t_s[c+2] * W2Ts[(c+2) * FD + t];
            s3 += t_s[c+3] * W2Ts[(c+3) * FD + t];
        }
        float du1 = (u1 > 0.f) ? ((s0 + s1) + (s2 + s3)) : 0.f;
        float p = du1 * ef;                      // s_ij = sum_f du1_f e_f
#pragma unroll
        for (int off = 32; off > 0; off >>= 1) p += __shfl_down(p, off);
        if ((t & 63) == 0) red[t >> 6] = p;
        __syncthreads();
        if (t == 0) S[i * N_ATOMS + j] = red[0] + red[1];
        // next-iteration writes to rbf_s/t_s are safe: reads completed before barrier;
        // red is rewritten only after the next barrier, which thread 0 must also reach.
    }
}

// ---------------------------------------------------------------- forces + dvdt + v copy
__global__ __launch_bounds__(64) void force_kernel(
    const float* __restrict__ q, const float* __restrict__ v,
    const float* __restrict__ mass, const float* __restrict__ p_eta,
    const float* __restrict__ S, const int* __restrict__ nbr_cnt,
    const int* __restrict__ nbr_idx, float* __restrict__ out)
{
    int i = blockIdx.x, t = threadIdx.x;
    float qx = q[i*3], qy = q[i*3+1], qz = q[i*3+2];
    int cnt = nbr_cnt[i];
    const int* nlist = nbr_idx + i * MAXN;
    float fx = 0.f, fy = 0.f, fz = 0.f;
    for (int jj = t; jj < cnt; jj += 64) {
        int j = nlist[jj];
        float dx = qx - q[j*3], dy = qy - q[j*3+1], dz = qz - q[j*3+2];
        float d = sqrtf(dx*dx + dy*dy + dz*dz);
        float s = S[i * N_ATOMS + j] + S[j * N_ATOMS + i];
        float cc = s / d;
        fx -= cc * dx; fy -= cc * dy; fz -= cc * dz;   // f = -dE/dq
    }
#pragma unroll
    for (int off = 32; off > 0; off >>= 1) {
        fx += __shfl_down(fx, off);
        fy += __shfl_down(fy, off);
        fz += __shfl_down(fz, off);
    }
    if (t == 0) {
        float mi = mass[i];
        float inv_mi = 1.f / mi;
        float c = p_eta[0] / Q0_F;               // coupled = peta0 * (v*m) / Q0
        float vx = v[i*3], vy = v[i*3+1], vz = v[i*3+2];
        out[DVDT_OFF + i*3 + 0] = (fx - c * vx * mi) * inv_mi;
        out[DVDT_OFF + i*3 + 1] = (fy - c * vy * mi) * inv_mi;
        out[DVDT_OFF + i*3 + 2] = (fz - c * vz * mi) * inv_mi;
        out[V_OFF + i*3 + 0] = vx;
        out[V_OFF + i*3 + 1] = vy;
        out[V_OFF + i*3 + 2] = vz;
    }
}

// ---------------------------------------------------------------- KE + dpeta_dt
__global__ __launch_bounds__(256) void finish_kernel(
    const float* __restrict__ v, const float* __restrict__ mass,
    const float* __restrict__ p_eta, float* __restrict__ out)
{
    __shared__ float red[256];
    int t = threadIdx.x;
    float acc = 0.f;
    for (int a = t; a < N_ATOMS; a += 256) {
        float vx = v[a*3], vy = v[a*3+1], vz = v[a*3+2];
        acc += 0.5f * mass[a] * (vx*vx + vy*vy + vz*vz);
    }
    red[t] = acc;
    __syncthreads();
    for (int s = 128; s > 0; s >>= 1) {
        if (t < s) red[t] += red[t + s];
        __syncthreads();
    }
    if (t == 0) {
        float ke = red[0];
        float e0 = p_eta[0], e1 = p_eta[1], e2 = p_eta[2], e3 = p_eta[3];
        out[PETA_OFF + 0] = 2.f * (ke - TARGET_KE) - e0 * e1 / QI_F;
        out[PETA_OFF + 1] = e0 * e0 / Q0_F - KT_F - e1 * e2 / QI_F;
        out[PETA_OFF + 2] = e1 * e1 / QI_F - KT_F - e2 * e3 / QI_F;
        out[PETA_OFF + 3] = e2 * e2 / QI_F - KT_F;
    }
}

// ---------------------------------------------------------------- launch
extern "C" void kernel_launch(void* const* d_in, const int* in_sizes, int n_in,
                              void* d_out, int out_size, void* d_ws, size_t ws_size,
                              hipStream_t stream)
{
    const float* v     = (const float*)d_in[0];
    const float* q     = (const float*)d_in[1];
    const float* p_eta = (const float*)d_in[2];
    const float* mass  = (const float*)d_in[3];
    const float* embed = (const float*)d_in[4];
    const float* W1    = (const float*)d_in[5];
    const float* b1    = (const float*)d_in[6];
    const float* W2    = (const float*)d_in[7];
    const float* b2    = (const float*)d_in[8];
    const float* W3    = (const float*)d_in[9];
    const float* wout  = (const float*)d_in[10];
    const int*   z     = (const int*)d_in[11];
    float* out = (float*)d_out;

    float* h    = (float*)d_ws;            // 98304
    float* W2T  = h + N_ATOMS * FD;        // 16384
    float* W3T  = W2T + FD * FD;           // 16384
    float* m    = W3T + FD * FD;           // 98304
    float* mbar = m + N_ATOMS * FD;        // 98304
    float* S    = mbar + N_ATOMS * FD;     // 589824
    int* nbr_cnt = (int*)(S + N_ATOMS * N_ATOMS);  // 768
    int* nbr_idx = nbr_cnt + N_ATOMS;              // 768*96

    size_t smem_fwd = (size_t)(FD * FD + NRBF + FD) * sizeof(float);
    size_t smem_bwd = (size_t)(FD * FD + 2 * NRBF + FD + 2) * sizeof(float);

    prep_kernel<<<384, 256, 0, stream>>>(z, embed, W2, W3, h, W2T, W3T);
    nbr_kernel<<<N_ATOMS, 256, 0, stream>>>(q, nbr_cnt, nbr_idx);
    fwd_kernel<<<N_ATOMS, 128, smem_fwd, stream>>>(q, W1, b1, W2, b2, h,
                                                   nbr_cnt, nbr_idx, m);
    mbar_kernel<<<N_ATOMS, 128, 0, stream>>>(m, W3, W3T, wout, mbar);
    bwd_kernel<<<N_ATOMS, 128, smem_bwd, stream>>>(q, W1, b1, W2T, h, mbar,
                                                   nbr_cnt, nbr_idx, S);
    force_kernel<<<N_ATOMS, 64, 0, stream>>>(q, v, mass, p_eta, S,
                                             nbr_cnt, nbr_idx, out);
    finish_kernel<<<1, 256, 0, stream>>>(v, mass, p_eta, out);
}

// Round 2
// 222.415 us; speedup vs baseline: 2.1032x; 2.1032x over previous
//
#include <hip/hip_runtime.h>
#include <math.h>

// Problem constants (match reference)
#define N_ATOMS 768
#define FD 128          // feature width F
#define NRBF 32
#define MAXN 96         // neighbor-list capacity (mean ~26)
#define PG 4            // pairs per group (register-blocked per wave)
#define NWAVE 4         // waves per block

constexpr float  CUT2   = 25.0f;
constexpr float  GAMMA_ = 40.96f;            // 1/(5/32)^2
constexpr float  CSTEP  = 5.0f / 31.0f;      // linspace(0,5,32) step
constexpr double KB_D   = 8.617330337217213e-05;
constexpr double KT_D   = 300.0 * KB_D;
constexpr float  KT_F   = (float)KT_D;
constexpr float  TARGET_KE = (float)(0.5 * 2304.0 * KT_D);
constexpr float  Q0_F   = (float)(2.0 * 2304.0 * KT_D * 400.0);  // Q[0]
constexpr float  QI_F   = (float)(2.0 * KT_D * 400.0);           // Q[1..3]

#define DVDT_OFF 0
#define V_OFF    (3 * N_ATOMS)
#define PETA_OFF (6 * N_ATOMS)

// ---------------------------------------------------------------- prep + neighbor list
// block i: neighbor list for atom i; spread h-gather / W2T,W3T transpose /
// f_acc zeroing across the grid by global thread id.
__global__ __launch_bounds__(256) void prep_nbr_kernel(
    const float* __restrict__ q, const int* __restrict__ z,
    const float* __restrict__ embed, const float* __restrict__ W2,
    const float* __restrict__ W3,
    float* __restrict__ h, float* __restrict__ W2T, float* __restrict__ W3T,
    float* __restrict__ f_acc, int* __restrict__ nbr_cnt, int* __restrict__ nbr_idx)
{
    __shared__ int c;
    int i = blockIdx.x, t = threadIdx.x;
    if (t == 0) c = 0;
    __syncthreads();
    float qx = q[i*3], qy = q[i*3+1], qz = q[i*3+2];
    for (int j = t; j < N_ATOMS; j += 256) {
        if (j == i) continue;
        float dx = qx - q[j*3], dy = qy - q[j*3+1], dz = qz - q[j*3+2];
        float d2 = dx*dx + dy*dy + dz*dz;
        if (d2 < CUT2) {
            int p = atomicAdd(&c, 1);
            if (p < MAXN) nbr_idx[i * MAXN + p] = j;
        }
    }
    int g = i * 256 + t;
    if (g < N_ATOMS * FD) h[g] = embed[z[g >> 7] * FD + (g & 127)];
    int g2 = g - N_ATOMS * FD;
    if (g2 >= 0 && g2 < FD * FD) {
        int r = g2 >> 7, cc = g2 & 127;
        W2T[cc * FD + r] = W2[g2];
        W3T[cc * FD + r] = W3[g2];
    }
    if (g < 3 * N_ATOMS) f_acc[g] = 0.f;
    __syncthreads();
    if (t == 0) nbr_cnt[i] = min(c, MAXN);
}

// ---------------------------------------------------------------- forward + mbar
// Block = atom i, 4 waves. Each wave handles neighbor groups of PG pairs with
// NO intra-loop __syncthreads (per-wave LDS scratch, wave-synchronous DS).
// Lane owns features f0=2*lane, f0+1. W2 read from global (L2-hot, amortized
// over PG pairs). Epilogue: cross-wave m reduce + mbar = W3@(wout*gate(mW3)).
__global__ __launch_bounds__(256) void fwd_kernel(
    const float* __restrict__ q, const float* __restrict__ W1,
    const float* __restrict__ b1, const float* __restrict__ W2,
    const float* __restrict__ b2, const float* __restrict__ h,
    const float* __restrict__ W3, const float* __restrict__ W3T,
    const float* __restrict__ wout,
    const int* __restrict__ nbr_cnt, const int* __restrict__ nbr_idx,
    float* __restrict__ mbar)
{
    __shared__ float qs[3 * N_ATOMS];        // 2304
    __shared__ float scr[NWAVE * 640];       // per wave: [0..127] rbf[p][k], [128..639] a1[p][f]
    __shared__ float red[NWAVE * FD];        // 512: cross-wave m partials

    int t = threadIdx.x, wave = t >> 6, lane = t & 63, i = blockIdx.x;
    int f0 = 2 * lane;

    for (int r = t; r < 3 * N_ATOMS / 4; r += 256)
        ((float4*)qs)[r] = ((const float4*)q)[r];

    float w1a[NRBF], w1b[NRBF];
#pragma unroll
    for (int k = 0; k < NRBF; k++) {
        float2 w = *(const float2*)(W1 + k * FD + f0);
        w1a[k] = w.x; w1b[k] = w.y;
    }
    float2 b1v = *(const float2*)(b1 + f0);
    float2 b2v = *(const float2*)(b2 + f0);
    int cnt = nbr_cnt[i];
    const int* nlist = nbr_idx + i * MAXN;
    float* ws  = scr + wave * 640;
    float* a1s = ws + 128;
    __syncthreads();   // qs ready (only barrier before epilogue)

    float qx = qs[i*3], qy = qs[i*3+1], qz = qs[i*3+2];
    float macc0 = 0.f, macc1 = 0.f;
    int ngroups = (cnt + PG - 1) / PG;

    for (int g = wave; g < ngroups; g += NWAVE) {
        int base = g * PG;
        int jj[PG]; float dd[PG]; bool val[PG]; float2 hj[PG];
#pragma unroll
        for (int p = 0; p < PG; p++) {
            int idx = base + p; val[p] = idx < cnt;
            int j = nlist[val[p] ? idx : cnt - 1];
            jj[p] = j;
            float dx = qx - qs[j*3], dy = qy - qs[j*3+1], dz = qz - qs[j*3+2];
            dd[p] = sqrtf(dx*dx + dy*dy + dz*dz);
            hj[p] = *(const float2*)(h + j * FD + f0);
        }
        // rbf: lane covers (p,k) = (lane>>4, 2*lane&31) and +1
        {
            int p = lane >> 4; int k = (2 * lane) & 31;
            float u0 = dd[p] - CSTEP * (float)k;
            float u1u = dd[p] - CSTEP * (float)(k + 1);
            float2 rv; rv.x = expf(-GAMMA_ * u0 * u0); rv.y = expf(-GAMMA_ * u1u * u1u);
            *(float2*)(ws + 2 * lane) = rv;
        }
        __builtin_amdgcn_wave_barrier();
        // u1 = b1 + rbf @ W1 (per pair, 2 features/lane)
        float u1a[PG], u1b[PG];
#pragma unroll
        for (int p = 0; p < PG; p++) { u1a[p] = b1v.x; u1b[p] = b1v.y; }
#pragma unroll
        for (int k4 = 0; k4 < NRBF / 4; k4++) {
#pragma unroll
            for (int p = 0; p < PG; p++) {
                float4 r = *(const float4*)(ws + p * 32 + k4 * 4);
                u1a[p] += r.x*w1a[k4*4] + r.y*w1a[k4*4+1] + r.z*w1a[k4*4+2] + r.w*w1a[k4*4+3];
                u1b[p] += r.x*w1b[k4*4] + r.y*w1b[k4*4+1] + r.z*w1b[k4*4+2] + r.w*w1b[k4*4+3];
            }
        }
#pragma unroll
        for (int p = 0; p < PG; p++) {
            float2 a; a.x = fmaxf(u1a[p], 0.f); a.y = fmaxf(u1b[p], 0.f);
            *(float2*)(a1s + p * FD + f0) = a;
        }
        __builtin_amdgcn_wave_barrier();
        // filt = a1 @ W2 (+b2): W2 rows from global (L2), a1 via LDS broadcast
        float dota[PG] = {0,0,0,0}, dotb[PG] = {0,0,0,0};
#pragma unroll 4
        for (int c4 = 0; c4 < FD / 4; c4++) {
            float2 w0 = *(const float2*)(W2 + (c4*4+0) * FD + f0);
            float2 w1v = *(const float2*)(W2 + (c4*4+1) * FD + f0);
            float2 w2v = *(const float2*)(W2 + (c4*4+2) * FD + f0);
            float2 w3v = *(const float2*)(W2 + (c4*4+3) * FD + f0);
#pragma unroll
            for (int p = 0; p < PG; p++) {
                float4 a = *(const float4*)(a1s + p * FD + c4 * 4);
                dota[p] += a.x*w0.x + a.y*w1v.x + a.z*w2v.x + a.w*w3v.x;
                dotb[p] += a.x*w0.y + a.y*w1v.y + a.z*w2v.y + a.w*w3v.y;
            }
        }
#pragma unroll
        for (int p = 0; p < PG; p++) {
            if (val[p]) {
                macc0 += (dota[p] + b2v.x) * hj[p].x;
                macc1 += (dotb[p] + b2v.y) * hj[p].y;
            }
        }
    }
    red[wave * FD + f0]     = macc0;
    red[wave * FD + f0 + 1] = macc1;
    __syncthreads();
    // ---- mbar epilogue (threads 0..127; scr reused post-barrier) ----
    if (t < FD) {
        float mf = red[t] + red[FD + t] + red[2*FD + t] + red[3*FD + t];
        scr[t] = mf;                         // ms
    }
    __syncthreads();
    if (t < FD) {
        float acc = 0.f;
#pragma unroll 4
        for (int c4 = 0; c4 < FD / 4; c4++) {
            float4 m4 = *(const float4*)(scr + c4 * 4);
            acc += m4.x * W3[(c4*4+0)*FD + t] + m4.y * W3[(c4*4+1)*FD + t]
                 + m4.z * W3[(c4*4+2)*FD + t] + m4.w * W3[(c4*4+3)*FD + t];
        }
        scr[FD + t] = (acc > 0.f) ? wout[t] : 0.f;   // gb
    }
    __syncthreads();
    if (t < FD) {
        float mb = 0.f;
#pragma unroll 4
        for (int c4 = 0; c4 < FD / 4; c4++) {
            float4 g4 = *(const float4*)(scr + FD + c4 * 4);
            mb += g4.x * W3T[(c4*4+0)*FD + t] + g4.y * W3T[(c4*4+1)*FD + t]
                + g4.z * W3T[(c4*4+2)*FD + t] + g4.w * W3T[(c4*4+3)*FD + t];
        }
        mbar[i * FD + t] = mb;
    }
}

// ---------------------------------------------------------------- backward + force atomics
// s_ij = gate(u1) .* (W2^T t) . ef, t = mbar_i*h_j; forces scattered with
// f32 atomics (f_i -= s*(qi-qj)/d, f_j += s*(qi-qj)/d).
__global__ __launch_bounds__(256) void bwd_kernel(
    const float* __restrict__ q, const float* __restrict__ W1,
    const float* __restrict__ b1, const float* __restrict__ W2T,
    const float* __restrict__ h, const float* __restrict__ mbar,
    const int* __restrict__ nbr_cnt, const int* __restrict__ nbr_idx,
    float* __restrict__ f_acc)
{
    __shared__ float qs[3 * N_ATOMS];        // 2304
    __shared__ float scr[NWAVE * 768];       // per wave: rbf[128], crbf[128], t[p][f] 512

    int t = threadIdx.x, wave = t >> 6, lane = t & 63, i = blockIdx.x;
    int f0 = 2 * lane;

    for (int r = t; r < 3 * N_ATOMS / 4; r += 256)
        ((float4*)qs)[r] = ((const float4*)q)[r];

    float w1a[NRBF], w1b[NRBF];
#pragma unroll
    for (int k = 0; k < NRBF; k++) {
        float2 w = *(const float2*)(W1 + k * FD + f0);
        w1a[k] = w.x; w1b[k] = w.y;
    }
    float2 b1v = *(const float2*)(b1 + f0);
    float2 mb  = *(const float2*)(mbar + i * FD + f0);
    int cnt = nbr_cnt[i];
    const int* nlist = nbr_idx + i * MAXN;
    float* rbfs  = scr + wave * 768;
    float* crbfs = rbfs + 128;
    float* ts    = crbfs + 128;
    __syncthreads();

    float qx = qs[i*3], qy = qs[i*3+1], qz = qs[i*3+2];
    int ngroups = (cnt + PG - 1) / PG;

    for (int g = wave; g < ngroups; g += NWAVE) {
        int base = g * PG;
        int jj[PG]; float dd[PG], dxr[PG], dyr[PG], dzr[PG]; bool val[PG];
#pragma unroll
        for (int p = 0; p < PG; p++) {
            int idx = base + p; val[p] = idx < cnt;
            int j = nlist[val[p] ? idx : cnt - 1];
            jj[p] = j;
            float dx = qx - qs[j*3], dy = qy - qs[j*3+1], dz = qz - qs[j*3+2];
            dxr[p] = dx; dyr[p] = dy; dzr[p] = dz;
            dd[p] = sqrtf(dx*dx + dy*dy + dz*dz);
            float2 hj = *(const float2*)(h + j * FD + f0);
            float2 tv; tv.x = mb.x * hj.x; tv.y = mb.y * hj.y;   // dE/dfilt
            *(float2*)(ts + p * FD + f0) = tv;
        }
        {
            int p = lane >> 4; int k = (2 * lane) & 31;
            float u0 = dd[p] - CSTEP * (float)k;
            float u1u = dd[p] - CSTEP * (float)(k + 1);
            float r0 = expf(-GAMMA_ * u0 * u0), r1 = expf(-GAMMA_ * u1u * u1u);
            float2 rv;  rv.x = r0;                       rv.y = r1;
            float2 cv;  cv.x = -2.f * GAMMA_ * u0 * r0;  cv.y = -2.f * GAMMA_ * u1u * r1;
            *(float2*)(rbfs  + 2 * lane) = rv;
            *(float2*)(crbfs + 2 * lane) = cv;
        }
        __builtin_amdgcn_wave_barrier();
        // u1 (gate) and ef = crbf @ W1
        float u1a[PG], u1b[PG], efa[PG], efb[PG];
#pragma unroll
        for (int p = 0; p < PG; p++) { u1a[p] = b1v.x; u1b[p] = b1v.y; efa[p] = 0.f; efb[p] = 0.f; }
#pragma unroll
        for (int k4 = 0; k4 < NRBF / 4; k4++) {
#pragma unroll
            for (int p = 0; p < PG; p++) {
                float4 r = *(const float4*)(rbfs  + p * 32 + k4 * 4);
                float4 c = *(const float4*)(crbfs + p * 32 + k4 * 4);
                u1a[p] += r.x*w1a[k4*4] + r.y*w1a[k4*4+1] + r.z*w1a[k4*4+2] + r.w*w1a[k4*4+3];
                u1b[p] += r.x*w1b[k4*4] + r.y*w1b[k4*4+1] + r.z*w1b[k4*4+2] + r.w*w1b[k4*4+3];
                efa[p] += c.x*w1a[k4*4] + c.y*w1a[k4*4+1] + c.z*w1a[k4*4+2] + c.w*w1a[k4*4+3];
                efb[p] += c.x*w1b[k4*4] + c.y*w1b[k4*4+1] + c.z*w1b[k4*4+2] + c.w*w1b[k4*4+3];
            }
        }
        // du1 = gate .* (t @ W2T): W2T rows from global, t via LDS broadcast
        float dota[PG] = {0,0,0,0}, dotb[PG] = {0,0,0,0};
#pragma unroll 4
        for (int c4 = 0; c4 < FD / 4; c4++) {
            float2 w0 = *(const float2*)(W2T + (c4*4+0) * FD + f0);
            float2 w1v = *(const float2*)(W2T + (c4*4+1) * FD + f0);
            float2 w2v = *(const float2*)(W2T + (c4*4+2) * FD + f0);
            float2 w3v = *(const float2*)(W2T + (c4*4+3) * FD + f0);
#pragma unroll
            for (int p = 0; p < PG; p++) {
                float4 a = *(const float4*)(ts + p * FD + c4 * 4);
                dota[p] += a.x*w0.x + a.y*w1v.x + a.z*w2v.x + a.w*w3v.x;
                dotb[p] += a.x*w0.y + a.y*w1v.y + a.z*w2v.y + a.w*w3v.y;
            }
        }
        float s[PG];
#pragma unroll
        for (int p = 0; p < PG; p++) {
            float da = (u1a[p] > 0.f) ? dota[p] : 0.f;
            float db = (u1b[p] > 0.f) ? dotb[p] : 0.f;
            s[p] = da * efa[p] + db * efb[p];
        }
#pragma unroll
        for (int off = 1; off < 64; off <<= 1) {
#pragma unroll
            for (int p = 0; p < PG; p++) s[p] += __shfl_xor(s[p], off, 64);
        }
        if (lane < PG && val[lane]) {
            int p = lane;
            float coef = s[p] / dd[p];
            float fx = coef * dxr[p], fy = coef * dyr[p], fz = coef * dzr[p];
            atomicAdd(f_acc + i*3 + 0, -fx);
            atomicAdd(f_acc + i*3 + 1, -fy);
            atomicAdd(f_acc + i*3 + 2, -fz);
            atomicAdd(f_acc + jj[p]*3 + 0, fx);
            atomicAdd(f_acc + jj[p]*3 + 1, fy);
            atomicAdd(f_acc + jj[p]*3 + 2, fz);
        }
    }
}

// ---------------------------------------------------------------- finalize: dvdt, v, KE, dpeta
__global__ __launch_bounds__(256) void fin_kernel(
    const float* __restrict__ v, const float* __restrict__ mass,
    const float* __restrict__ p_eta, const float* __restrict__ f_acc,
    float* __restrict__ out)
{
    __shared__ float red[256];
    int t = threadIdx.x;
    float ke = 0.f;
    float c = p_eta[0] / Q0_F;
    for (int idx = t; idx < 3 * N_ATOMS; idx += 256) {
        int a = idx / 3;
        float vv = v[idx], mi = mass[a];
        out[DVDT_OFF + idx] = (f_acc[idx] - c * vv * mi) / mi;
        out[V_OFF + idx] = vv;
        ke += 0.5f * mi * vv * vv;
    }
    red[t] = ke;
    __syncthreads();
    for (int s = 128; s > 0; s >>= 1) {
        if (t < s) red[t] += red[t + s];
        __syncthreads();
    }
    if (t == 0) {
        float k0 = red[0];
        float e0 = p_eta[0], e1 = p_eta[1], e2 = p_eta[2], e3 = p_eta[3];
        out[PETA_OFF + 0] = 2.f * (k0 - TARGET_KE) - e0 * e1 / QI_F;
        out[PETA_OFF + 1] = e0 * e0 / Q0_F - KT_F - e1 * e2 / QI_F;
        out[PETA_OFF + 2] = e1 * e1 / QI_F - KT_F - e2 * e3 / QI_F;
        out[PETA_OFF + 3] = e2 * e2 / QI_F - KT_F;
    }
}

// ---------------------------------------------------------------- launch
extern "C" void kernel_launch(void* const* d_in, const int* in_sizes, int n_in,
                              void* d_out, int out_size, void* d_ws, size_t ws_size,
                              hipStream_t stream)
{
    const float* v     = (const float*)d_in[0];
    const float* q     = (const float*)d_in[1];
    const float* p_eta = (const float*)d_in[2];
    const float* mass  = (const float*)d_in[3];
    const float* embed = (const float*)d_in[4];
    const float* W1    = (const float*)d_in[5];
    const float* b1    = (const float*)d_in[6];
    const float* W2    = (const float*)d_in[7];
    const float* b2    = (const float*)d_in[8];
    const float* W3    = (const float*)d_in[9];
    const float* wout  = (const float*)d_in[10];
    const int*   z     = (const int*)d_in[11];
    float* out = (float*)d_out;

    float* h     = (float*)d_ws;            // 98304
    float* W2T   = h + N_ATOMS * FD;        // 16384
    float* W3T   = W2T + FD * FD;           // 16384
    float* mbar  = W3T + FD * FD;           // 98304
    float* f_acc = mbar + N_ATOMS * FD;     // 2304
    int* nbr_cnt = (int*)(f_acc + 3 * N_ATOMS);  // 768
    int* nbr_idx = nbr_cnt + N_ATOMS;            // 768*96

    prep_nbr_kernel<<<N_ATOMS, 256, 0, stream>>>(q, z, embed, W2, W3, h, W2T,
                                                 W3T, f_acc, nbr_cnt, nbr_idx);
    fwd_kernel<<<N_ATOMS, 256, 0, stream>>>(q, W1, b1, W2, b2, h, W3, W3T,
                                            wout, nbr_cnt, nbr_idx, mbar);
    bwd_kernel<<<N_ATOMS, 256, 0, stream>>>(q, W1, b1, W2T, h, mbar,
                                            nbr_cnt, nbr_idx, f_acc);
    fin_kernel<<<1, 256, 0, stream>>>(v, mass, p_eta, f_acc, out);
}